// Round 4
// baseline (388.864 us; speedup 1.0000x reference)
//
#include <hip/hip_runtime.h>

// ShiftingLayer: out = zeros(H,W); out[i + trunc(wr[i,j]), j + trunc(wc[i,j])] = x[i,j]
// (OOB targets dropped). H=4096, W=8192, fp32.
//
// R3 post-mortem: fused 4-stream kernel (read x,wr,wc + write out) is pinned
// at 3.58 TB/s logical / 2.35 TB/s HBM REGARDLESS of load batching (VGPR 28
// vs 52), CPT (4 vs 8) or occupancy (74% vs 37%) — not latency/issue/
// occupancy-bound. Theory: 4-stream R/W mix through L2/LLC/fabric caps well
// below the 2-stream copy ceiling (6.29 TB/s, m13).
//
// R4 structure: decompose into 2-stream phases.
//   1. copy_kernel:   out = x           (pure copy, 256 MB traffic)
//   2. scan_kernel:   read wr/wc, append nonzero-shift chunks to worklist
//                     (pure 256 MB read; empty worklist for bench inputs)
//   3. fix_zero:      zero shifted-source positions  (worklist; empty -> exit)
//   4. fix_scatter:   write x to in-bounds targets   (worklist; empty -> exit)
// Ordering (all zeroes before any scatters, separate dispatches) preserves
// general-case semantics exactly like the previous place/scatter split.
//
// Prev-session lesson: __builtin_nontemporal_store regressed streaming
// stores ~10% at identical traffic — plain stores only.

constexpr int H = 4096;
constexpr int W = 8192;                         // 2^13
constexpr long long TOTAL  = (long long)H * W;  // 33,554,432
constexpr long long NCHUNK = TOTAL / 4;         // 8,388,608 float4 chunks
constexpr int BLOCK = 256;
constexpr int CPT   = 4;                        // chunks per thread

typedef float vf4 __attribute__((ext_vector_type(4)));

// ---- worklist path -------------------------------------------------------

__global__ __launch_bounds__(64) void init_ws_kernel(unsigned* __restrict__ ws) {
    if (threadIdx.x == 0) ws[0] = 0u;           // d_ws is poisoned 0xAA each call
}

// Phase 1: out = x. Pure 2-stream copy at copy-class BW.
__global__ __launch_bounds__(BLOCK) void copy_kernel(
    const float* __restrict__ x,
    float* __restrict__ out)
{
    const long long chunk0 = (long long)blockIdx.x * (BLOCK * CPT) + threadIdx.x;
    vf4 v[CPT];
    #pragma unroll
    for (int u = 0; u < CPT; ++u)
        v[u] = *reinterpret_cast<const vf4*>(x + (chunk0 + (long long)u * BLOCK) * 4);
    #pragma unroll
    for (int u = 0; u < CPT; ++u)
        *reinterpret_cast<vf4*>(out + (chunk0 + (long long)u * BLOCK) * 4) = v[u];
}

// Phase 2: pure read of wr/wc; worklist-append chunks with any nonzero shift.
__global__ __launch_bounds__(BLOCK) void scan_kernel(
    const float* __restrict__ wr,
    const float* __restrict__ wc,
    unsigned* __restrict__ ws_count,
    unsigned* __restrict__ ws_list)
{
    const long long chunk0 = (long long)blockIdx.x * (BLOCK * CPT) + threadIdx.x;
    #pragma unroll
    for (int u = 0; u < CPT; ++u) {
        const long long chunk = chunk0 + (long long)u * BLOCK;
        const long long base  = chunk * 4;
        const vf4 rv = *reinterpret_cast<const vf4*>(wr + base);
        const vf4 cv = *reinterpret_cast<const vf4*>(wc + base);
        // C float->int cast truncates toward zero == jnp.trunc + astype(int32)
        const int m = ((int)rv.x | (int)rv.y | (int)rv.z | (int)rv.w |
                       (int)cv.x | (int)cv.y | (int)cv.z | (int)cv.w);
        if (m != 0) {
            unsigned slot = atomicAdd(ws_count, 1u);   // device-scope default
            ws_list[slot] = (unsigned)chunk;
        }
    }
}

// Phase 3: zero the source positions of shifted elements (out[i,j] was set
// to x[i,j] by the copy; reference drops those values).
__global__ __launch_bounds__(BLOCK) void fix_zero_kernel(
    const float* __restrict__ wr,
    const float* __restrict__ wc,
    float* __restrict__ out,
    const unsigned* __restrict__ ws_count,
    const unsigned* __restrict__ ws_list)
{
    const unsigned count  = ws_count[0];
    const unsigned stride = gridDim.x * blockDim.x;
    for (unsigned i = blockIdx.x * blockDim.x + threadIdx.x; i < count; i += stride) {
        const long long base = (long long)ws_list[i] * 4;
        const vf4 rv = *reinterpret_cast<const vf4*>(wr + base);
        const vf4 cv = *reinterpret_cast<const vf4*>(wc + base);
        if (((int)rv.x | (int)cv.x) != 0) out[base + 0] = 0.0f;
        if (((int)rv.y | (int)cv.y) != 0) out[base + 1] = 0.0f;
        if (((int)rv.z | (int)cv.z) != 0) out[base + 2] = 0.0f;
        if (((int)rv.w | (int)cv.w) != 0) out[base + 3] = 0.0f;
    }
}

// Phase 4: scatter shifted elements to their in-bounds targets.
__global__ __launch_bounds__(BLOCK) void fix_scatter_kernel(
    const float* __restrict__ x,
    const float* __restrict__ wr,
    const float* __restrict__ wc,
    float* __restrict__ out,
    const unsigned* __restrict__ ws_count,
    const unsigned* __restrict__ ws_list)
{
    const unsigned count  = ws_count[0];
    const unsigned stride = gridDim.x * blockDim.x;
    for (unsigned i = blockIdx.x * blockDim.x + threadIdx.x; i < count; i += stride) {
        const long long base = (long long)ws_list[i] * 4;
        const int row = (int)(base >> 13);
        const int col = (int)(base & (W - 1));

        const vf4 xv = *reinterpret_cast<const vf4*>(x  + base);
        const vf4 rv = *reinterpret_cast<const vf4*>(wr + base);
        const vf4 cv = *reinterpret_cast<const vf4*>(wc + base);

        int rs, cs, tr, tc;
        rs = (int)rv.x; cs = (int)cv.x;
        if ((rs | cs) != 0) { tr = row + rs; tc = col + 0 + cs;
            if ((unsigned)tr < (unsigned)H && (unsigned)tc < (unsigned)W)
                out[(long long)tr * W + tc] = xv.x; }
        rs = (int)rv.y; cs = (int)cv.y;
        if ((rs | cs) != 0) { tr = row + rs; tc = col + 1 + cs;
            if ((unsigned)tr < (unsigned)H && (unsigned)tc < (unsigned)W)
                out[(long long)tr * W + tc] = xv.y; }
        rs = (int)rv.z; cs = (int)cv.z;
        if ((rs | cs) != 0) { tr = row + rs; tc = col + 2 + cs;
            if ((unsigned)tr < (unsigned)H && (unsigned)tc < (unsigned)W)
                out[(long long)tr * W + tc] = xv.z; }
        rs = (int)rv.w; cs = (int)cv.w;
        if ((rs | cs) != 0) { tr = row + rs; tc = col + 3 + cs;
            if ((unsigned)tr < (unsigned)H && (unsigned)tc < (unsigned)W)
                out[(long long)tr * W + tc] = xv.w; }
    }
}

// ---- fallback path (if d_ws too small): zero + full scatter --------------

__global__ __launch_bounds__(BLOCK) void zero_out_kernel(float* __restrict__ out) {
    long long tid = (long long)blockIdx.x * blockDim.x + threadIdx.x;
    vf4 z = {0.f, 0.f, 0.f, 0.f};
    *reinterpret_cast<vf4*>(out + tid * 4) = z;
}

__global__ __launch_bounds__(BLOCK) void shift_scatter_kernel(
    const float* __restrict__ x,
    const float* __restrict__ wr,
    const float* __restrict__ wc,
    float* __restrict__ out)
{
    long long tid  = (long long)blockIdx.x * blockDim.x + threadIdx.x;
    long long base = tid * 4;
    int row = (int)(base >> 13);
    int col = (int)(base & (W - 1));

    const vf4 xv = *reinterpret_cast<const vf4*>(x  + base);
    const vf4 rv = *reinterpret_cast<const vf4*>(wr + base);
    const vf4 cv = *reinterpret_cast<const vf4*>(wc + base);

    int rs0 = (int)rv.x, rs1 = (int)rv.y, rs2 = (int)rv.z, rs3 = (int)rv.w;
    int cs0 = (int)cv.x, cs1 = (int)cv.y, cs2 = (int)cv.z, cs3 = (int)cv.w;

    if (((rs0 | rs1 | rs2 | rs3) | (cs0 | cs1 | cs2 | cs3)) == 0) {
        *reinterpret_cast<vf4*>(out + base) = xv;
        return;
    }
    int tr, tc;
    tr = row + rs0; tc = col + 0 + cs0;
    if ((unsigned)tr < (unsigned)H && (unsigned)tc < (unsigned)W)
        out[(long long)tr * W + tc] = xv.x;
    tr = row + rs1; tc = col + 1 + cs1;
    if ((unsigned)tr < (unsigned)H && (unsigned)tc < (unsigned)W)
        out[(long long)tr * W + tc] = xv.y;
    tr = row + rs2; tc = col + 2 + cs2;
    if ((unsigned)tr < (unsigned)H && (unsigned)tc < (unsigned)W)
        out[(long long)tr * W + tc] = xv.z;
    tr = row + rs3; tc = col + 3 + cs3;
    if ((unsigned)tr < (unsigned)H && (unsigned)tc < (unsigned)W)
        out[(long long)tr * W + tc] = xv.w;
}

// ---- launch --------------------------------------------------------------

extern "C" void kernel_launch(void* const* d_in, const int* in_sizes, int n_in,
                              void* d_out, int out_size, void* d_ws, size_t ws_size,
                              hipStream_t stream) {
    const float* x  = (const float*)d_in[0];
    const float* wr = (const float*)d_in[1];
    const float* wc = (const float*)d_in[2];
    float* out = (float*)d_out;

    // worklist layout in d_ws: [0] counter (unsigned), [16..] chunk indices
    const size_t ws_needed = 16 + (size_t)NCHUNK * sizeof(unsigned);

    if (ws_size >= ws_needed) {
        unsigned* ws_count = (unsigned*)d_ws;
        unsigned* ws_list  = (unsigned*)((char*)d_ws + 16);
        const int grid = (int)(NCHUNK / (BLOCK * CPT));     // 8192 blocks
        init_ws_kernel<<<1, 64, 0, stream>>>(ws_count);
        copy_kernel<<<grid, BLOCK, 0, stream>>>(x, out);
        scan_kernel<<<grid, BLOCK, 0, stream>>>(wr, wc, ws_count, ws_list);
        fix_zero_kernel<<<256, BLOCK, 0, stream>>>(wr, wc, out,
                                                   ws_count, ws_list);
        fix_scatter_kernel<<<256, BLOCK, 0, stream>>>(x, wr, wc, out,
                                                      ws_count, ws_list);
    } else {
        const int grid = (int)(NCHUNK / BLOCK);             // 32768 blocks
        zero_out_kernel<<<grid, BLOCK, 0, stream>>>(out);
        shift_scatter_kernel<<<grid, BLOCK, 0, stream>>>(x, wr, wc, out);
    }
}